// Round 14
// baseline (175.050 us; speedup 1.0000x reference)
//
#include <hip/hip_runtime.h>

// VectorQuantizer: x (32,64,64,64) f32, codebook (1024,64) f32
// out = concat( quantized (32,64,64,64) f32 , indices (32,64,64) as f32 )
//
// R18b = R18 resubmitted unchanged (container died at infra level twice, no
// verify/counters — same signature as R7, which ran clean on resubmit).
// Audit found no hang mechanism: ring identical to verified R13/R14/R15;
// 32x32x16 intrinsic + reg counts valid; merge writes each row once.
//
// R18 = 32x32x16 MFMA shape (half the MFMA instructions, faster pipe).
//  - R17 post-mortem: barrier-free pipelines null (8th). All variants share
//    one invariant: 3.15M x 16x16x32 MFMAs. Busy-sum model (~35-40us serial)
//    vs measured 66us leaves ~25-30us stall that must scale with the shared
//    invariant => test per-MFMA-instruction overhead: v_mfma_f32_32x32x16
//    halves instruction count at same FLOPs, and its ubench rate is 10-15%
//    better (2382-2495 vs 2075-2176 TF).
//  - layouts: C/D = HW-verified m74/m101 (col=lane&31, row=(r&3)+8*(r>>2)
//    +4*(lane>>5)). A/B: row/col=lane&31, k=8*(lane>>5)+j (doubled-K analog
//    of our verified 16x16x32 layout; identical k-convention on A and B =>
//    any internal k-permutation cancels in the dot product).
//  - wave = 32 pos (one 32-row M-tile), block 128 pos, grid 1024; chunk =
//    one 32-code tile = 8KB; R13's VERIFIED ring (4 slots, vmcnt(4)/2/0,
//    2 gloads/wave/chunk) unchanged. Per chunk/wave: 12 MFMA in 3 depth-4
//    chains (pa=Ci+Ak.B, pb=Ah.R, pc=Ra.B), 16 keys x 5 VALU.
//  - numerics: same q-unit int keys, EPS_Q 24 (regroup error << margin),
//    exact-f32 rescan. absmax is the layout tripwire.

typedef _Float16 f16x8  __attribute__((ext_vector_type(8)));
typedef float    f32x16 __attribute__((ext_vector_type(16)));

#define VQ_D    64
#define VQ_HW   4096
#define VQ_NPOS 131072
#define SC      2048.0f
#define EPS_Q   24         // flag margin in q-units (24/2048 = 1.17e-2)
// ws float offsets (stream = 32 chunks * 8192B = 256KB = 65536 floats)
#define WS_CBN  65536      // f32 cn[1024] raw (rescan)
#define WS_CNQ  66560      // f32 cn_q[1024] = 2048*cn (main C-init)
#define WS_CBT  67584      // float4 cbT4[16384] (256 KB)
#define WS_CNT  133120     // int rescan counter
#define WS_LIST 133124     // int list[131072]

// ---------- prep ----------
// stream item it = ct32*512 + s*256 + kq*64 + lane, f16x8 each.
// s: 0=bh2, 1=rb2k. value for code n=ct32*32+(lane&31),
// dim k = kq*16 + (lane>>5)*8 + j. byte addr = it*16.
__global__ __launch_bounds__(256)
void vq_prep(const float* __restrict__ cb, float* __restrict__ ws)
{
    const int tid = threadIdx.x;
    const int blk = blockIdx.x;
    if (blk < 64) {
        const int it   = blk * 256 + tid;            // [0, 16384)
        const int ct32 = it >> 9;                    // [0, 32)
        const int s    = (it >> 8) & 1;
        const int kq   = (it >> 6) & 3;
        const int lane = it & 63;
        const int n    = ct32 * 32 + (lane & 31);    // code (B column)
        const int k0   = kq * 16 + (lane >> 5) * 8;  // dim  (B row)
        const float* src = cb + n * 64 + k0;
        f16x8 o;
        #pragma unroll
        for (int j = 0; j < 8; ++j) {
            const float b = src[j];
            const _Float16 bh = (_Float16)b;
            o[j] = s ? (_Float16)((b - (float)bh) * (-2.0f * SC))
                     : (_Float16)(-2.0f * (float)bh);
        }
        ((f16x8*)ws)[it] = o;
    } else if (blk < 128) {
        const int it = (blk - 64) * 256 + tid;       // [0, 16384)
        const int k = it >> 4, j4 = it & 15;
        ((float4*)(ws + WS_CBT))[j4 * 1024 + k] = ((const float4*)cb)[it];
    } else {
        const int k = (blk - 128) * 256 + tid;       // [0, 1024)
        const float4* row = (const float4*)(cb + k * 64);
        float a0 = 0.f, a1 = 0.f, a2 = 0.f, a3 = 0.f;
        #pragma unroll
        for (int j = 0; j < 16; ++j) {
            const float4 c = row[j];
            a0 = fmaf(c.x, c.x, a0); a1 = fmaf(c.y, c.y, a1);
            a2 = fmaf(c.z, c.z, a2); a3 = fmaf(c.w, c.w, a3);
        }
        const float cn = (a0 + a1) + (a2 + a3);
        ws[WS_CBN + k] = cn;                         // raw (rescan)
        ws[WS_CNQ + k] = cn * 2048.0f;               // q-units (main)
        if (k == 0) ((int*)ws)[WS_CNT] = 0;
    }
}

// ---------- main ----------
#define GLOAD_LDS(GP, LP)                                                     \
    __builtin_amdgcn_global_load_lds(                                         \
        (const __attribute__((address_space(1))) unsigned int*)(GP),          \
        (__attribute__((address_space(3))) unsigned int*)(LP), 16, 0, 0)

// stage 8KB chunk CK into ring slot byte-offset BOFF: 2 gloads per wave
#define STAGE2(CK, BOFF)                                                      \
    {                                                                         \
        const char* gs_ = (const char*)ws + (size_t)(CK) * 8192               \
                          + wv * 2048 + lane * 16;                            \
        char* ld_ = (char*)bbuf + (BOFF) + wv * 2048;                         \
        GLOAD_LDS(gs_, ld_);                                                  \
        GLOAD_LDS(gs_ + 1024, ld_ + 1024);                                    \
    }

// one 32-code tile: 12 x mfma_32x32x16 in 3 independent depth-4 chains,
// then 16 keys x (add,add,cvt,shl|or,med3,min).
#define CT32_BODY(BOFF, CT32)                                                 \
    {                                                                         \
        const f16x8 B0 = *(const f16x8*)(lp + (BOFF));                        \
        const f16x8 B1 = *(const f16x8*)(lp + (BOFF) + 1024);                 \
        const f16x8 B2 = *(const f16x8*)(lp + (BOFF) + 2048);                 \
        const f16x8 B3 = *(const f16x8*)(lp + (BOFF) + 3072);                 \
        const f16x8 R0 = *(const f16x8*)(lp + (BOFF) + 4096);                 \
        const f16x8 R1 = *(const f16x8*)(lp + (BOFF) + 5120);                 \
        const f16x8 R2 = *(const f16x8*)(lp + (BOFF) + 6144);                 \
        const f16x8 R3 = *(const f16x8*)(lp + (BOFF) + 7168);                 \
        const float cvq = cnq_lds[(CT32) * 32 + (lane & 31)];                 \
        f32x16 Ci;                                                            \
        _Pragma("unroll")                                                     \
        for (int r = 0; r < 16; ++r) Ci[r] = cvq;                             \
        __builtin_amdgcn_s_setprio(1);                                        \
        f32x16 pa = __builtin_amdgcn_mfma_f32_32x32x16_f16(Ak[0], B0, Ci,     0,0,0); \
        f32x16 pb = __builtin_amdgcn_mfma_f32_32x32x16_f16(Ah[0], R0, zero16, 0,0,0); \
        f32x16 pc = __builtin_amdgcn_mfma_f32_32x32x16_f16(Ra[0], B0, zero16, 0,0,0); \
        pa = __builtin_amdgcn_mfma_f32_32x32x16_f16(Ak[1], B1, pa, 0,0,0);    \
        pb = __builtin_amdgcn_mfma_f32_32x32x16_f16(Ah[1], R1, pb, 0,0,0);    \
        pc = __builtin_amdgcn_mfma_f32_32x32x16_f16(Ra[1], B1, pc, 0,0,0);    \
        pa = __builtin_amdgcn_mfma_f32_32x32x16_f16(Ak[2], B2, pa, 0,0,0);    \
        pb = __builtin_amdgcn_mfma_f32_32x32x16_f16(Ah[2], R2, pb, 0,0,0);    \
        pc = __builtin_amdgcn_mfma_f32_32x32x16_f16(Ra[2], B2, pc, 0,0,0);    \
        pa = __builtin_amdgcn_mfma_f32_32x32x16_f16(Ak[3], B3, pa, 0,0,0);    \
        pb = __builtin_amdgcn_mfma_f32_32x32x16_f16(Ah[3], R3, pb, 0,0,0);    \
        pc = __builtin_amdgcn_mfma_f32_32x32x16_f16(Ra[3], B3, pc, 0,0,0);    \
        __builtin_amdgcn_s_setprio(0);                                        \
        const int cbase_ = (CT32) * 32 + (lane & 31);                         \
        _Pragma("unroll")                                                     \
        for (int r = 0; r < 16; ++r) {                                        \
            const float q_ = (pa[r] + pb[r]) + pc[r];                         \
            const int k_ = ((int)q_ << 10) | cbase_;                          \
            int md_;                                                          \
            asm("v_med3_i32 %0, %1, %2, %3"                                   \
                : "=v"(md_) : "v"(k_), "v"(d1[r]), "v"(d2[r]));               \
            d2[r] = md_;                                                      \
            d1[r] = (k_ < d1[r]) ? k_ : d1[r];                                \
        }                                                                     \
    }

// ring iteration: wait own chunk-T loads (counted), sync, prefetch T+3,
// compute chunk T (one 32-code tile). VMSTR = counted vmcnt literal.
#define ITER_T(VMSTR, DOSTAGE, T)                                             \
    {                                                                         \
        asm volatile("s_waitcnt " VMSTR ::: "memory");                        \
        __builtin_amdgcn_s_barrier();                                         \
        if (DOSTAGE) STAGE2((T) + 3, (((T) + 3) & 3) * 8192)                  \
        CT32_BODY(((T) & 3) * 8192, T)                                        \
    }

__global__ __launch_bounds__(256, 2)
void vq_main(const float* __restrict__ x,
             const float* __restrict__ cb,
             float* __restrict__ ws,
             float* __restrict__ out,
             float* __restrict__ idx_out)
{
    __shared__ f16x8 bbuf[4 * 512];   // 4-slot ring, 8KB (one ct32) per slot
    __shared__ float cnq_lds[1024];   // 2048*||e||^2
    __shared__ int   sk[128];
    __shared__ int   smg[128];

    const int tid  = threadIdx.x;
    const int lane = tid & 63;
    const int wv   = tid >> 6;        // 4 waves, 32 positions each

    const int p0 = blockIdx.x * 128;  // block: 128 consecutive positions
    const int b  = p0 >> 12;
    const int n0 = p0 & (VQ_HW - 1);
    const float* xw = x + (size_t)b * (VQ_D * VQ_HW) + n0 + wv * 32;

    // prologue: stage chunks 0..2 (latency hidden under A build + cn fill)
    STAGE2(0, 0)
    STAGE2(1, 8192)
    STAGE2(2, 16384)

    // cn_q -> LDS (once)
    ((float4*)cnq_lds)[tid] = ((const float4*)(ws + WS_CNQ))[tid];

    // ---- A fragments: hi, 2048*hi (exact), scaled residual; 1 M-tile of 32,
    // layout row=lane&31, k = kq*16 + (lane>>5)*8 + j ----
    f16x8 Ah[4], Ak[4], Ra[4];
    #pragma unroll
    for (int kq = 0; kq < 4; ++kq) {
        f16x8 h8, k8, r8;
        #pragma unroll
        for (int j = 0; j < 8; ++j) {
            const int k = kq * 16 + (lane >> 5) * 8 + j;
            const float v = xw[(size_t)k * VQ_HW + (lane & 31)];
            const _Float16 vh = (_Float16)v;
            h8[j] = vh;
            k8[j] = (_Float16)((float)vh * 2048.0f);     // exact (pow2)
            r8[j] = (_Float16)((v - (float)vh) * SC);
        }
        Ah[kq] = h8; Ak[kq] = k8; Ra[kq] = r8;
    }

    int d1[16], d2[16];
    #pragma unroll
    for (int r = 0; r < 16; ++r) { d1[r] = 0x7FFFFFFF; d2[r] = 0x7FFFFFFF; }

    f32x16 zero16;
    #pragma unroll
    for (int r = 0; r < 16; ++r) zero16[r] = 0.0f;
    const char* lp = (const char*)bbuf + lane * 16;

    __syncthreads();   // one-time full drain: c0-c2 + cnq_lds resident

    // ---- main ring: counted vmcnt, loads stay in flight across barriers ----
    for (int t = 0; t < 29; ++t)
        ITER_T("vmcnt(4)", 1, t)      // steady state: wait oldest of 3 chunks
    ITER_T("vmcnt(4)", 0, 29)         // c29: outstanding c29..c31 -> 4
    ITER_T("vmcnt(2)", 0, 30)         // c30: outstanding c30,c31  -> 2
    ITER_T("vmcnt(0)", 0, 31)         // c31: last

    // ---- top-2 merge across the 32 code-columns (keys carry the code) ----
    #pragma unroll
    for (int off = 1; off < 32; off <<= 1)
        #pragma unroll
        for (int r = 0; r < 16; ++r) {
            const int od1 = __shfl_xor(d1[r], off, 64);
            const int od2 = __shfl_xor(d2[r], off, 64);
            const int mx  = (d1[r] > od1) ? d1[r] : od1;
            const int mn2 = (d2[r] < od2) ? d2[r] : od2;
            d2[r] = (mx < mn2) ? mx : mn2;
            d1[r] = (d1[r] < od1) ? d1[r] : od1;
        }

    if ((lane & 31) == 0) {
        #pragma unroll
        for (int r = 0; r < 16; ++r) {
            const int row = (r & 3) + 8 * (r >> 2) + 4 * (lane >> 5);
            const int li  = wv * 32 + row;
            sk[li]  = d1[r] & 1023;
            smg[li] = (d2[r] >> 10) - (d1[r] >> 10);   // gap, q-units
        }
    }
    __syncthreads();

    // ---- epilogue: indices, rescan flags, quantized scatter ----
    const int pos  = tid & 127;
    const int half = tid >> 7;        // 2 threads per position, 32 dims each
    const int bk   = sk[pos];
    if (half == 0) {
        idx_out[p0 + pos] = (float)bk;
        if (smg[pos] < EPS_Q) {
            const int slot = atomicAdd((int*)ws + WS_CNT, 1);
            ((int*)ws)[WS_LIST + slot] = p0 + pos;
        }
    }
    const float4* cr = (const float4*)(cb + (size_t)bk * VQ_D) + half * 8;
    float* ob = out + (size_t)b * (VQ_D * VQ_HW) + (size_t)(half * 32) * VQ_HW + n0 + pos;
    #pragma unroll
    for (int d4 = 0; d4 < 8; ++d4) {
        const float4 v = cr[d4];
        ob[(size_t)(d4 * 4 + 0) * VQ_HW] = v.x;
        ob[(size_t)(d4 * 4 + 1) * VQ_HW] = v.y;
        ob[(size_t)(d4 * 4 + 2) * VQ_HW] = v.z;
        ob[(size_t)(d4 * 4 + 3) * VQ_HW] = v.w;
    }
}

// ---------- rescan: exact f32 argmin for flagged positions (verified) ----------
__global__ __launch_bounds__(64)
void vq_rescan(const float* __restrict__ x,
               const float* __restrict__ cb,
               const float* __restrict__ ws,
               float* __restrict__ out,
               float* __restrict__ idx_out)
{
    __shared__ float xs[VQ_D];
    const int lane = threadIdx.x;
    const int cnt  = ((const int*)ws)[WS_CNT];
    const int* list = (const int*)ws + WS_LIST;
    const float*  cnb  = ws + WS_CBN;
    const float4* cbT4 = (const float4*)(ws + WS_CBT);

    for (int i = blockIdx.x; i < cnt; i += gridDim.x) {
        const int p = list[i];
        const int b = p >> 12, n = p & (VQ_HW - 1);
        xs[lane] = x[(size_t)b * (VQ_D * VQ_HW) + (size_t)lane * VQ_HW + n];
        __syncthreads();
        float4 xr[16];
        #pragma unroll
        for (int j = 0; j < 16; ++j) xr[j] = ((const float4*)xs)[j];

        float bd = 3.4e38f; int bk = 0;
        #pragma unroll 4
        for (int t = 0; t < 16; ++t) {
            const int code = t * 64 + lane;           // per-lane ascending
            float a0 = 0.f, a1 = 0.f, a2 = 0.f, a3 = 0.f;
            #pragma unroll
            for (int j4 = 0; j4 < 16; ++j4) {
                const float4 c = cbT4[j4 * 1024 + code];   // coalesced
                a0 = fmaf(xr[j4].x, c.x, a0); a1 = fmaf(xr[j4].y, c.y, a1);
                a2 = fmaf(xr[j4].z, c.z, a2); a3 = fmaf(xr[j4].w, c.w, a3);
            }
            const float dist = fmaf(-2.0f, (a0 + a1) + (a2 + a3), cnb[code]);
            if (dist < bd) { bd = dist; bk = code; }
        }
        #pragma unroll
        for (int off = 1; off < 64; off <<= 1) {      // min dist, tie -> min k
            const float od = __shfl_xor(bd, off, 64);
            const int   ok = __shfl_xor(bk, off, 64);
            if (od < bd || (od == bd && ok < bk)) { bd = od; bk = ok; }
        }
        out[(size_t)b * (VQ_D * VQ_HW) + (size_t)lane * VQ_HW + n] = cb[(size_t)bk * VQ_D + lane];
        if (lane == 0) idx_out[p] = (float)bk;
        __syncthreads();
    }
}

extern "C" void kernel_launch(void* const* d_in, const int* in_sizes, int n_in,
                              void* d_out, int out_size, void* d_ws, size_t ws_size,
                              hipStream_t stream) {
    const float* x  = (const float*)d_in[0];
    const float* cb = (const float*)d_in[1];
    float* out = (float*)d_out;
    float* idx = out + (size_t)VQ_NPOS * VQ_D;   // 8,388,608 floats in
    float* ws  = (float*)d_ws;                    // ~1.06 MB used

    vq_prep  <<<dim3(132),  dim3(256), 0, stream>>>(cb, ws);
    vq_main  <<<dim3(1024), dim3(256), 0, stream>>>(x, cb, ws, out, idx);
    vq_rescan<<<dim3(1024), dim3(64),  0, stream>>>(x, cb, ws, out, idx);
}

// Round 15
// 140.855 us; speedup vs baseline: 1.2428x; 1.2428x over previous
//
#include <hip/hip_runtime.h>

// VectorQuantizer: x (32,64,64,64) f32, codebook (1024,64) f32
// out = concat( quantized (32,64,64,64) f32 , indices (32,64,64) as f32 )
//
// R19 = R15 (best verified structure) + INLINE per-block rescan; 2 kernels.
//  - R18 post-mortem: 32x32x16 shape falsified per-MFMA-overhead theory and
//    regressed (88us, MfmaUtil 24): fewer/longer MFMAs expose more chain
//    latency. 10th structural null -> main is at an empirical plateau
//    (~66us, 2.6x the 24.8us MFMA floor). Revert to R15.
//  - Attack the TOTAL instead: best totals 155.4/155.5 carry ~88us non-main
//    (prep + rescan + 2 kernel boundaries). Flags are strictly block-local
//    (each position belongs to one main block), so the exact rescan moves
//    INTO the main epilogue: LDS flag list, waves round-robin positions,
//    verbatim vq_rescan math (same cbT4/cn/fmaf order), overwrite idx/out
//    after a barrier. vq_rescan kernel deleted -> one boundary fewer.
//  - ring/math byte-identical to R15 (q-unit int keys, EPS_Q 24, absmax 0).
//  - decision: total ~135-148 => boundary overhead was real; total ~155 =>
//    harness floor, declare limit.

typedef _Float16 f16x8 __attribute__((ext_vector_type(8)));
typedef float    f32x4 __attribute__((ext_vector_type(4)));

#define VQ_D    64
#define VQ_HW   4096
#define VQ_NPOS 131072
#define SC      2048.0f
#define EPS_Q   24         // flag margin in q-units (24/2048 = 1.17e-2)
// ws float offsets (stream = 32 chunks * 8192B = 256KB = 65536 floats)
#define WS_CBN  65536      // f32 cn[1024] raw (inline rescan)
#define WS_CNQ  66560      // f32 cn_q[1024] = 2048*cn (main C-init)
#define WS_CBT  67584      // float4 cbT4[16384] (256 KB)

// ---------- prep (identical to R13/R14/R15, verified) ----------
__global__ __launch_bounds__(256)
void vq_prep(const float* __restrict__ cb, float* __restrict__ ws)
{
    const int tid = threadIdx.x;
    const int blk = blockIdx.x;
    if (blk < 64) {
        const int it   = blk * 256 + tid;            // [0, 16384)
        const int ct   = it >> 8;
        const int s    = (it >> 6) & 3;
        const int lane = it & 63;
        const int ks   = s & 1, isR = s >> 1;
        const int n    = ct * 16 + (lane & 15);      // code (B column)
        const int k0   = ks * 32 + (lane >> 4) * 8;  // dim  (B row)
        const float* src = cb + n * 64 + k0;
        f16x8 o;
        #pragma unroll
        for (int j = 0; j < 8; ++j) {
            const float b = src[j];
            const _Float16 bh = (_Float16)b;
            o[j] = isR ? (_Float16)((b - (float)bh) * (-2.0f * SC))
                       : (_Float16)(-2.0f * (float)bh);
        }
        ((f16x8*)ws)[it] = o;
    } else if (blk < 128) {
        const int it = (blk - 64) * 256 + tid;       // [0, 16384)
        const int k = it >> 4, j4 = it & 15;
        ((float4*)(ws + WS_CBT))[j4 * 1024 + k] = ((const float4*)cb)[it];
    } else {
        const int k = (blk - 128) * 256 + tid;       // [0, 1024)
        const float4* row = (const float4*)(cb + k * 64);
        float a0 = 0.f, a1 = 0.f, a2 = 0.f, a3 = 0.f;
        #pragma unroll
        for (int j = 0; j < 16; ++j) {
            const float4 c = row[j];
            a0 = fmaf(c.x, c.x, a0); a1 = fmaf(c.y, c.y, a1);
            a2 = fmaf(c.z, c.z, a2); a3 = fmaf(c.w, c.w, a3);
        }
        const float cn = (a0 + a1) + (a2 + a3);
        ws[WS_CBN + k] = cn;                         // raw (rescan)
        ws[WS_CNQ + k] = cn * 2048.0f;               // q-units (main)
    }
}

// ---------- main ----------
#define GLOAD_LDS(GP, LP)                                                     \
    __builtin_amdgcn_global_load_lds(                                         \
        (const __attribute__((address_space(1))) unsigned int*)(GP),          \
        (__attribute__((address_space(3))) unsigned int*)(LP), 16, 0, 0)

// stage 8KB chunk CK into ring slot byte-offset BOFF: 2 gloads per wave
#define STAGE2(CK, BOFF)                                                      \
    {                                                                         \
        const char* gs_ = (const char*)ws + (size_t)(CK) * 8192               \
                          + wv * 2048 + lane * 16;                            \
        char* ld_ = (char*)bbuf + (BOFF) + wv * 2048;                         \
        GLOAD_LDS(gs_, ld_);                                                  \
        GLOAD_LDS(gs_ + 1024, ld_ + 1024);                                    \
    }

// one 16-code tile, 4 M-tiles: 8 independent depth-3 chains (pa/pb per tile),
// 24 MFMAs; then 1 add + int-key update per output (16 outputs).
#define CT_BODY(BOFF, CI, CTG)                                                \
    {                                                                         \
        const f16x8 B0 = *(const f16x8*)(lp + (BOFF) + (CI) * 4096);          \
        const f16x8 B1 = *(const f16x8*)(lp + (BOFF) + (CI) * 4096 + 1024);   \
        const f16x8 R0 = *(const f16x8*)(lp + (BOFF) + (CI) * 4096 + 2048);   \
        const f16x8 R1 = *(const f16x8*)(lp + (BOFF) + (CI) * 4096 + 3072);   \
        const float cvq = cnq_lds[(CTG) * 16 + m];                            \
        const f32x4 Ci = {cvq, cvq, cvq, cvq};                                \
        f32x4 pa[4], pb[4];                                                   \
        __builtin_amdgcn_s_setprio(1);                                        \
        _Pragma("unroll")                                                     \
        for (int tl = 0; tl < 4; ++tl) {                                      \
            pa[tl] = __builtin_amdgcn_mfma_f32_16x16x32_f16(Ak[tl][0], B0, Ci,    0,0,0); \
            pb[tl] = __builtin_amdgcn_mfma_f32_16x16x32_f16(Ak[tl][1], B1, zero4, 0,0,0); \
        }                                                                     \
        _Pragma("unroll")                                                     \
        for (int tl = 0; tl < 4; ++tl) {                                      \
            pa[tl] = __builtin_amdgcn_mfma_f32_16x16x32_f16(Ah[tl][0], R0, pa[tl], 0,0,0); \
            pb[tl] = __builtin_amdgcn_mfma_f32_16x16x32_f16(Ah[tl][1], R1, pb[tl], 0,0,0); \
        }                                                                     \
        _Pragma("unroll")                                                     \
        for (int tl = 0; tl < 4; ++tl) {                                      \
            pa[tl] = __builtin_amdgcn_mfma_f32_16x16x32_f16(Ra[tl][0], B0, pa[tl], 0,0,0); \
            pb[tl] = __builtin_amdgcn_mfma_f32_16x16x32_f16(Ra[tl][1], B1, pb[tl], 0,0,0); \
        }                                                                     \
        __builtin_amdgcn_s_setprio(0);                                        \
        const int cbase_ = (CTG) * 16 + m;                                    \
        _Pragma("unroll")                                                     \
        for (int tl = 0; tl < 4; ++tl)                                        \
            _Pragma("unroll")                                                 \
            for (int r = 0; r < 4; ++r) {                                     \
                const float q_ = pa[tl][r] + pb[tl][r];                       \
                const int k_ = ((int)q_ << 10) | cbase_;                      \
                int md_;                                                      \
                asm("v_med3_i32 %0, %1, %2, %3"                               \
                    : "=v"(md_) : "v"(k_), "v"(d1[tl][r]), "v"(d2[tl][r]));   \
                d2[tl][r] = md_;                                              \
                d1[tl][r] = (k_ < d1[tl][r]) ? k_ : d1[tl][r];                \
            }                                                                 \
    }

// ring iteration: wait own chunk-T loads (counted), sync, prefetch T+3,
// compute chunk T (2 ct). VMSTR is the counted vmcnt literal.
#define ITER_T(VMSTR, DOSTAGE, T)                                             \
    {                                                                         \
        asm volatile("s_waitcnt " VMSTR ::: "memory");                        \
        __builtin_amdgcn_s_barrier();                                         \
        if (DOSTAGE) STAGE2((T) + 3, (((T) + 3) & 3) * 8192)                  \
        const int base_ = ((T) & 3) * 8192;                                   \
        CT_BODY(base_, 0, (T) * 2)                                            \
        CT_BODY(base_, 1, (T) * 2 + 1)                                        \
    }

__global__ __launch_bounds__(256, 2)
void vq_main(const float* __restrict__ x,
             const float* __restrict__ cb,
             float* __restrict__ ws,
             float* __restrict__ out,
             float* __restrict__ idx_out)
{
    __shared__ f16x8 bbuf[4 * 512];   // 4-slot ring, 8KB (2 ct) per slot
    __shared__ float cnq_lds[1024];   // 2048*||e||^2
    __shared__ int   sk[256];
    __shared__ int   smg[256];
    __shared__ int   lpos[256];       // flagged-position list (block-local)
    __shared__ int   lcnt;

    const int tid  = threadIdx.x;
    const int lane = tid & 63;
    const int wv   = tid >> 6;        // 4 waves, 64 positions each
    const int m    = lane & 15;
    const int q    = lane >> 4;

    const int p0 = blockIdx.x * 256;  // block: 256 consecutive positions
    const int b  = p0 >> 12;
    const int n0 = p0 & (VQ_HW - 1);
    const float* xw = x + (size_t)b * (VQ_D * VQ_HW) + n0 + wv * 64;

    // prologue: stage chunks 0..2 (latency hidden under A build + cn fill)
    STAGE2(0, 0)
    STAGE2(1, 8192)
    STAGE2(2, 16384)

    // cn_q -> LDS (once)
    ((float4*)cnq_lds)[tid] = ((const float4*)(ws + WS_CNQ))[tid];

    // ---- A fragments: hi, 2048*hi (exact), scaled residual; 4 M-tiles ----
    f16x8 Ah[4][2], Ak[4][2], Ra[4][2];
    #pragma unroll
    for (int tl = 0; tl < 4; ++tl)
        #pragma unroll
        for (int ks = 0; ks < 2; ++ks) {
            f16x8 h8, k8, r8;
            #pragma unroll
            for (int j = 0; j < 8; ++j) {
                const float v = xw[(size_t)(ks * 32 + q * 8 + j) * VQ_HW + tl * 16 + m];
                const _Float16 vh = (_Float16)v;
                h8[j] = vh;
                k8[j] = (_Float16)((float)vh * 2048.0f);     // exact (pow2)
                r8[j] = (_Float16)((v - (float)vh) * SC);
            }
            Ah[tl][ks] = h8; Ak[tl][ks] = k8; Ra[tl][ks] = r8;
        }

    int d1[4][4], d2[4][4];
    #pragma unroll
    for (int tl = 0; tl < 4; ++tl)
        #pragma unroll
        for (int r = 0; r < 4; ++r) { d1[tl][r] = 0x7FFFFFFF; d2[tl][r] = 0x7FFFFFFF; }

    const f32x4 zero4 = {0.f, 0.f, 0.f, 0.f};
    const char* lp = (const char*)bbuf + lane * 16;

    __syncthreads();   // one-time full drain: c0-c2 + cnq_lds resident

    // ---- main ring: counted vmcnt, loads stay in flight across barriers ----
    for (int t = 0; t < 29; ++t)
        ITER_T("vmcnt(4)", 1, t)      // steady state: wait oldest of 3 chunks
    ITER_T("vmcnt(4)", 0, 29)         // c29: outstanding c29..c31 -> 4
    ITER_T("vmcnt(2)", 0, 30)         // c30: outstanding c30,c31  -> 2
    ITER_T("vmcnt(0)", 0, 31)         // c31: last

    // ---- top-2 merge across the 16 code-columns (keys carry the code) ----
    #pragma unroll
    for (int off = 1; off < 16; off <<= 1)
        #pragma unroll
        for (int tl = 0; tl < 4; ++tl)
            #pragma unroll
            for (int r = 0; r < 4; ++r) {
                const int od1 = __shfl_xor(d1[tl][r], off, 64);
                const int od2 = __shfl_xor(d2[tl][r], off, 64);
                const int mx  = (d1[tl][r] > od1) ? d1[tl][r] : od1;
                const int mn2 = (d2[tl][r] < od2) ? d2[tl][r] : od2;
                d2[tl][r] = (mx < mn2) ? mx : mn2;
                d1[tl][r] = (d1[tl][r] < od1) ? d1[tl][r] : od1;
            }

    if (m == 0) {
        #pragma unroll
        for (int tl = 0; tl < 4; ++tl)
            #pragma unroll
            for (int r = 0; r < 4; ++r) {
                const int li = wv * 64 + tl * 16 + q * 4 + r;
                sk[li]  = d1[tl][r] & 1023;
                smg[li] = (d2[tl][r] >> 10) - (d1[tl][r] >> 10);   // gap, q-units
            }
    }
    if (tid == 0) lcnt = 0;
    __syncthreads();

    // ---- epilogue: indices + approximate quantized scatter ----
    const int bk = sk[tid];           // 1 thread per position
    idx_out[p0 + tid] = (float)bk;
    {
        const float4* cr = (const float4*)(cb + (size_t)bk * VQ_D);
        float* ob = out + (size_t)b * (VQ_D * VQ_HW) + n0 + tid;
        #pragma unroll
        for (int d4 = 0; d4 < 16; ++d4) {
            const float4 v = cr[d4];
            ob[(size_t)(d4 * 4 + 0) * VQ_HW] = v.x;
            ob[(size_t)(d4 * 4 + 1) * VQ_HW] = v.y;
            ob[(size_t)(d4 * 4 + 2) * VQ_HW] = v.z;
            ob[(size_t)(d4 * 4 + 3) * VQ_HW] = v.w;
        }
    }
    if (smg[tid] < EPS_Q) {           // collect flags (block-local)
        const int s_ = atomicAdd(&lcnt, 1);
        lpos[s_] = tid;
    }
    __syncthreads();

    // ---- inline exact-f32 rescan of flagged positions (verbatim math) ----
    const int nf = lcnt;
    if (nf > 0) {
        const float*  cnb  = ws + WS_CBN;
        const float4* cbT4 = (const float4*)(ws + WS_CBT);
        float* xsw = (float*)((char*)bbuf + wv * 1024);   // ring is dead; reuse
        for (int i = wv; i < nf; i += 4) {                // waves round-robin
            const int pos = lpos[i];
            const int nn  = n0 + pos;
            xsw[lane] = x[(size_t)b * (VQ_D * VQ_HW) + (size_t)lane * VQ_HW + nn];
            float4 xr[16];
            #pragma unroll
            for (int j = 0; j < 16; ++j) xr[j] = ((const float4*)xsw)[j];

            float bd = 3.4e38f; int bk2 = 0;
            #pragma unroll 4
            for (int t = 0; t < 16; ++t) {
                const int code = t * 64 + lane;           // per-lane ascending
                float a0 = 0.f, a1 = 0.f, a2 = 0.f, a3 = 0.f;
                #pragma unroll
                for (int j4 = 0; j4 < 16; ++j4) {
                    const float4 c = cbT4[j4 * 1024 + code];   // coalesced
                    a0 = fmaf(xr[j4].x, c.x, a0); a1 = fmaf(xr[j4].y, c.y, a1);
                    a2 = fmaf(xr[j4].z, c.z, a2); a3 = fmaf(xr[j4].w, c.w, a3);
                }
                const float dist = fmaf(-2.0f, (a0 + a1) + (a2 + a3), cnb[code]);
                if (dist < bd) { bd = dist; bk2 = code; }
            }
            #pragma unroll
            for (int off = 1; off < 64; off <<= 1) {      // min dist, tie -> min k
                const float od = __shfl_xor(bd, off, 64);
                const int   ok = __shfl_xor(bk2, off, 64);
                if (od < bd || (od == bd && ok < bk2)) { bd = od; bk2 = ok; }
            }
            out[(size_t)b * (VQ_D * VQ_HW) + (size_t)lane * VQ_HW + nn] =
                cb[(size_t)bk2 * VQ_D + lane];
            if (lane == 0) idx_out[p0 + pos] = (float)bk2;
        }
    }
}

extern "C" void kernel_launch(void* const* d_in, const int* in_sizes, int n_in,
                              void* d_out, int out_size, void* d_ws, size_t ws_size,
                              hipStream_t stream) {
    const float* x  = (const float*)d_in[0];
    const float* cb = (const float*)d_in[1];
    float* out = (float*)d_out;
    float* idx = out + (size_t)VQ_NPOS * VQ_D;   // 8,388,608 floats in
    float* ws  = (float*)d_ws;                    // ~1.06 MB used

    vq_prep<<<dim3(132), dim3(256), 0, stream>>>(cb, ws);
    vq_main<<<dim3(512), dim3(256), 0, stream>>>(x, cb, ws, out, idx);
}